// Round 1
// baseline (13508.780 us; speedup 1.0000x reference)
//
#include <hip/hip_runtime.h>
#include <hip/hip_bf16.h>

#define B 32
#define S 512
#define H 1024
#define G 4096          // 4*H
#define M (B*S)         // 16384
#define KSPLIT 4
#define KRANGE (H/KSPLIT)   // 256
#define KCH 64
#define UNITS 32

// ---------- xz storage type helpers ----------
__device__ __forceinline__ void store_xz(float* p, float v) { *p = v; }
__device__ __forceinline__ void store_xz(__hip_bfloat16* p, float v) { *p = __float2bfloat16(v); }
__device__ __forceinline__ float load_xz(const float* p) { return *p; }
__device__ __forceinline__ float load_xz(const __hip_bfloat16* p) { return __bfloat162float(*p); }

// =====================================================================
// Kernel 1: xz[dir][m][g] = x[m][:] @ W_dir   (bias added later)
// 128x128 tile, 256 threads, 8x8 microtile, fp32
// =====================================================================
template<typename TXZ>
__global__ __launch_bounds__(256)
void xz_gemm(const float* __restrict__ x,
             const float* __restrict__ Wfw, const float* __restrict__ Wbw,
             TXZ* __restrict__ xz)
{
    const int dir = blockIdx.z;
    const float* Wt = dir ? Wbw : Wfw;
    TXZ* out = xz + (size_t)dir * M * G;

    const int bm = blockIdx.y * 128;
    const int bn = blockIdx.x * 128;
    const int tid = threadIdx.x;
    const int tx = tid & 15, ty = tid >> 4;

    __shared__ float Asm[16][132];   // [k][m]
    __shared__ float Bsm[16][132];   // [k][n]

    float acc[8][8];
#pragma unroll
    for (int i = 0; i < 8; ++i)
#pragma unroll
        for (int j = 0; j < 8; ++j) acc[i][j] = 0.f;

    for (int k0 = 0; k0 < H; k0 += 16) {
        // A tile: 128 rows x 16 k  (512 float4)
#pragma unroll
        for (int l = 0; l < 2; ++l) {
            int idx = tid + l * 256;
            int row = idx >> 2, kq = (idx & 3) * 4;
            float4 v = *(const float4*)&x[(size_t)(bm + row) * H + k0 + kq];
            Asm[kq + 0][row] = v.x; Asm[kq + 1][row] = v.y;
            Asm[kq + 2][row] = v.z; Asm[kq + 3][row] = v.w;
        }
        // B tile: 16 k x 128 cols (512 float4)
#pragma unroll
        for (int l = 0; l < 2; ++l) {
            int idx = tid + l * 256;
            int kr = idx >> 5, nq = (idx & 31) * 4;
            *(float4*)&Bsm[kr][nq] = *(const float4*)&Wt[(size_t)(k0 + kr) * G + bn + nq];
        }
        __syncthreads();
#pragma unroll
        for (int k = 0; k < 16; ++k) {
            float a[8], b[8];
            *(float4*)&a[0] = *(const float4*)&Asm[k][ty * 8];
            *(float4*)&a[4] = *(const float4*)&Asm[k][ty * 8 + 4];
            *(float4*)&b[0] = *(const float4*)&Bsm[k][tx * 8];
            *(float4*)&b[4] = *(const float4*)&Bsm[k][tx * 8 + 4];
#pragma unroll
            for (int i = 0; i < 8; ++i)
#pragma unroll
                for (int j = 0; j < 8; ++j)
                    acc[i][j] = fmaf(a[i], b[j], acc[i][j]);
        }
        __syncthreads();
    }
#pragma unroll
    for (int i = 0; i < 8; ++i) {
        size_t r = (size_t)(bm + ty * 8 + i) * G + bn + tx * 8;
#pragma unroll
        for (int j = 0; j < 8; ++j) store_xz(&out[r + j], acc[i][j]);
    }
}

// =====================================================================
// Kernel 2 (per step): zpart[dir][ks][b][g] = sum_{k in ks-range} h[b][k]*U[k][g]
// grid (32 jgroups, 4 ksplit, 2 dir), 256 threads
// thread: 32-unit group col jj, batch quad bq -> acc[4 gates][4 b]
// =====================================================================
__global__ __launch_bounds__(256)
void zpart_kernel(const float* __restrict__ hbuf,
                  const float* __restrict__ Ufw, const float* __restrict__ Ubw,
                  float* __restrict__ zpart)
{
    const int jg  = blockIdx.x;
    const int ks  = blockIdx.y;
    const int dir = blockIdx.z;
    const float* U = dir ? Ubw : Ufw;
    const float* h = hbuf + dir * B * H;
    const int j0 = jg * UNITS;
    const int kbase = ks * KRANGE;

    const int t  = threadIdx.x;
    const int jj = t & 31;
    const int bq = t >> 5;   // 0..7 -> b = bq*4+bi

    __shared__ float hs[KCH][B];          // 8 KB, [k][b]
    __shared__ float us[KCH][4 * UNITS];  // 32 KB, [k][gate*32+jj]

    float acc[4][4];
#pragma unroll
    for (int q = 0; q < 4; ++q)
#pragma unroll
        for (int bi = 0; bi < 4; ++bi) acc[q][bi] = 0.f;

    for (int kc = 0; kc < KRANGE; kc += KCH) {
        const int k0 = kbase + kc;
        // stage h chunk: 64k x 32b (512 float4)
#pragma unroll
        for (int l = 0; l < 2; ++l) {
            int idx = t + l * 256;
            int b = idx >> 4, kq = (idx & 15) * 4;
            float4 v = *(const float4*)&h[b * H + k0 + kq];
            hs[kq + 0][b] = v.x; hs[kq + 1][b] = v.y;
            hs[kq + 2][b] = v.z; hs[kq + 3][b] = v.w;
        }
        // stage U chunk: 64k x 128 cols (4 gate groups of 32) (2048 float4)
#pragma unroll
        for (int l = 0; l < 8; ++l) {
            int idx = t + l * 256;
            int kr = idx >> 5, c4 = idx & 31;
            int q = c4 >> 3, w = c4 & 7;
            *(float4*)&us[kr][q * UNITS + w * 4] =
                *(const float4*)&U[(size_t)(k0 + kr) * G + q * H + j0 + w * 4];
        }
        __syncthreads();
#pragma unroll
        for (int k = 0; k < KCH; ++k) {
            float hv[4];
            *(float4*)&hv[0] = *(const float4*)&hs[k][bq * 4];
            float u0 = us[k][0 * UNITS + jj];
            float u1 = us[k][1 * UNITS + jj];
            float u2 = us[k][2 * UNITS + jj];
            float u3 = us[k][3 * UNITS + jj];
#pragma unroll
            for (int bi = 0; bi < 4; ++bi) {
                acc[0][bi] = fmaf(u0, hv[bi], acc[0][bi]);
                acc[1][bi] = fmaf(u1, hv[bi], acc[1][bi]);
                acc[2][bi] = fmaf(u2, hv[bi], acc[2][bi]);
                acc[3][bi] = fmaf(u3, hv[bi], acc[3][bi]);
            }
        }
        __syncthreads();
    }
#pragma unroll
    for (int q = 0; q < 4; ++q)
#pragma unroll
        for (int bi = 0; bi < 4; ++bi) {
            int b = bq * 4 + bi;
            zpart[(((size_t)dir * KSPLIT + ks) * B + b) * G + q * H + j0 + jj] = acc[q][bi];
        }
}

// =====================================================================
// Kernel 3 (per step): reduce ksplit partials + xz + bias, gates, state
// update, masked carry, write encoder output (and final states at t=S-1)
// 65536 cells = 2 dir x 32 b x 1024 j
// =====================================================================
template<typename TXZ>
__global__ __launch_bounds__(256)
void gate_kernel(const float* __restrict__ zpart,
                 const TXZ* __restrict__ xz,
                 const float* __restrict__ bfw, const float* __restrict__ bbw,
                 const float* __restrict__ pad,
                 float* __restrict__ hbuf, float* __restrict__ cbuf,
                 float* __restrict__ dout, int t)
{
    int cell = blockIdx.x * 256 + threadIdx.x;
    int j = cell & (H - 1);
    int b = (cell >> 10) & 31;
    int dir = cell >> 15;
    int s = dir ? (S - 1 - t) : t;
    const float* bias = dir ? bbw : bfw;

    float z[4];
#pragma unroll
    for (int q = 0; q < 4; ++q) {
        int g = q * H + j;
        float a = load_xz(&xz[((size_t)dir * M + (size_t)b * S + s) * G + g]) + bias[g];
#pragma unroll
        for (int ks = 0; ks < KSPLIT; ++ks)
            a += zpart[(((size_t)dir * KSPLIT + ks) * B + b) * G + g];
        z[q] = a;
    }
    float ig = 1.f / (1.f + expf(-z[0]));
    float fg = 1.f / (1.f + expf(-z[1]));
    float gg = tanhf(z[2]);
    float og = 1.f / (1.f + expf(-z[3]));

    int hidx = dir * B * H + b * H + j;
    float cold = cbuf[hidx], hold = hbuf[hidx];
    float cn = fg * cold + ig * gg;
    float hn = og * tanhf(cn);
    float m = 1.f - pad[b * S + s];
    float h2 = fmaf(m, hn - hold, hold);
    float c2 = fmaf(m, cn - cold, cold);
    hbuf[hidx] = h2;
    cbuf[hidx] = c2;

    dout[((size_t)b * S + s) * (2 * H) + dir * H + j] = h2;

    if (t == S - 1) {
        size_t base = (size_t)B * S * 2 * H;
        dout[base + dir * 2 * B * H + b * H + j] = h2;           // h_fw / h_bw
        dout[base + dir * 2 * B * H + B * H + b * H + j] = c2;   // c_fw / c_bw
    }
}

// =====================================================================
// Host side
// =====================================================================
template<typename TXZ>
static void run_all(const float* x, const float* pad,
                    const float* Wfw, const float* Ufw, const float* bfw,
                    const float* Wbw, const float* Ubw, const float* bbw,
                    float* out, void* d_ws, hipStream_t stream)
{
    char* w = (char*)d_ws;
    size_t xz_bytes = (size_t)2 * M * G * sizeof(TXZ);
    TXZ* xz = (TXZ*)w;
    float* hbuf = (float*)(w + xz_bytes);
    float* cbuf = hbuf + 2 * B * H;
    float* zpart = cbuf + 2 * B * H;

    // zero h and c (deterministic per call)
    hipMemsetAsync(hbuf, 0, (size_t)2 * 2 * B * H * sizeof(float), stream);

    dim3 gg(G / 128, M / 128, 2);
    xz_gemm<TXZ><<<gg, 256, 0, stream>>>(x, Wfw, Wbw, xz);

    for (int t = 0; t < S; ++t) {
        zpart_kernel<<<dim3(H / UNITS / 1, KSPLIT, 2), 256, 0, stream>>>(hbuf, Ufw, Ubw, zpart);
        gate_kernel<TXZ><<<dim3(65536 / 256), 256, 0, stream>>>(zpart, xz, bfw, bbw, pad,
                                                                hbuf, cbuf, out, t);
    }
}

extern "C" void kernel_launch(void* const* d_in, const int* in_sizes, int n_in,
                              void* d_out, int out_size, void* d_ws, size_t ws_size,
                              hipStream_t stream)
{
    const float* x   = (const float*)d_in[0];
    const float* pad = (const float*)d_in[1];
    const float* Wfw = (const float*)d_in[2];
    const float* Ufw = (const float*)d_in[3];
    const float* bfw = (const float*)d_in[4];
    const float* Wbw = (const float*)d_in[5];
    const float* Ubw = (const float*)d_in[6];
    const float* bbw = (const float*)d_in[7];
    float* out = (float*)d_out;

    const size_t aux_bytes = (size_t)(2 * 2 * B * H) * sizeof(float)       // h + c
                           + (size_t)2 * KSPLIT * B * G * sizeof(float);   // zpart
    const size_t need_f32  = (size_t)2 * M * G * sizeof(float) + aux_bytes;
    const size_t need_bf16 = (size_t)2 * M * G * sizeof(__hip_bfloat16) + aux_bytes;

    if (ws_size >= need_f32) {
        run_all<float>(x, pad, Wfw, Ufw, bfw, Wbw, Ubw, bbw, out, d_ws, stream);
    } else if (ws_size >= need_bf16) {
        run_all<__hip_bfloat16>(x, pad, Wfw, Ufw, bfw, Wbw, Ubw, bbw, out, d_ws, stream);
    }
    // else: workspace too small — nothing safe to do (will fail validation loudly)
}